// Round 10
// baseline (48.295 us; speedup 1.0000x reference)
//
#include <hip/hip_runtime.h>
#include <hip/hip_bf16.h>

typedef __attribute__((ext_vector_type(8))) short bf16x8;
typedef __attribute__((ext_vector_type(4))) float f32x4;

#define CC 128
#define KK 128
#define HH 56
#define WW 56
#define HW (HH * WW)

#define XP_OFF (512 * 1024)  // ws: wt at 0 (288KB), xp at 512KB (15.7MB)
#define BUFSZ 12288          // A 8KB + B 4KB
#define ROWB (16 * 66 * 16)  // xp bytes per padded row (16 cp * 66 w * 16B)

__device__ __forceinline__ unsigned short f2bf(float f) {
  unsigned int u = __builtin_bit_cast(unsigned int, f);
  u += 0x7FFFu + ((u >> 16) & 1u);
  return (unsigned short)(u >> 16);
}

__device__ __forceinline__ void gload_lds16(const void* g, void* l) {
  __builtin_amdgcn_global_load_lds((__attribute__((address_space(1))) void*)g,
                                   (__attribute__((address_space(3))) void*)l,
                                   16, 0, 0);
}

// K0 merged: blocks 0..3827 = prepack (x fp32 NCHW -> xp bf16 cells:
// idx = ((n*58+h)*16+cp)*66+w, halo zeroed); blocks 3828..4403 = wtrans
// (kernel -> wt bf16: e = (((t*2+kn)*4+p)*64 + l)*8 + j, t=rs*4+cs,
// k=kn*64+l, c=cs*32+p*8+j).
__global__ void prep_kernel(const float* __restrict__ x,
                            const float* __restrict__ kin,
                            unsigned short* __restrict__ xp,
                            unsigned short* __restrict__ wt) {
  int b = blockIdx.x;
  if (b < 3828) {
    int idx = b * 256 + threadIdx.x;  // 979968 exact
    int w = idx % 66;
    int q = idx / 66;
    int cp = q & 15;
    int r = q >> 4;
    int h = r % 58;
    int n = r / 58;
    bool ok = (h >= 1) && (h <= 56) && (w >= 1) && (w <= 56);
    const float* src =
        x + ((size_t)(n * CC + cp * 8) * HH + (h - 1)) * WW + (w - 1);
    unsigned short o[8];
#pragma unroll
    for (int ci = 0; ci < 8; ++ci) {
      float v = ok ? src[(size_t)ci * HW] : 0.f;
      o[ci] = f2bf(v);
    }
    *(bf16x8*)(xp + (size_t)idx * 8) = *(bf16x8*)o;
  } else {
    int e = (b - 3828) * 256 + threadIdx.x;  // 147456 exact
    int j = e & 7;
    int l = (e >> 3) & 63;
    int p = (e >> 9) & 3;
    int kn = (e >> 11) & 1;
    int t = e >> 12;  // 0..35
    int rs = t >> 2;
    int cs = t & 3;
    int k = kn * 64 + l;
    int c = cs * 32 + p * 8 + j;
    wt[e] = f2bf(kin[(k * CC + c) * 9 + rs]);
  }
}

// K1: conv as GEMM, mfma_f32_16x16x32_bf16. Grid 896 (16n x 28hp x 2kn,
// XCD-swizzled), 128 thr (2 waves) -> 3.5 blocks/CU. Block: M=112 px
// (2 rows x 56 w, padded to 128) x N=64 k. 36 K-steps of BK=32c.
// LDS: 4 bufs x 12KB (A [4cp][128px][16B] + B [4cp][64k][16B]); staging via
// global_load_lds depth-3 (counted vmcnt(12), drain 6 -> 0 at tail).
__global__ __launch_bounds__(128, 2) void conv_kernel(
    const unsigned short* __restrict__ xp, const unsigned short* __restrict__ wt,
    float* __restrict__ out) {
  __shared__ __align__(16) unsigned char xs[4 * BUFSZ];  // 48 KB

  const int tid = threadIdx.x;
  const int lane = tid & 63;
  const int wv = tid >> 6;  // 0..1 (M-half of frags; also stages parts 2wv,2wv+1)

  const int b = blockIdx.x;
  const int wg = (b & 7) * 112 + (b >> 3);  // XCD swizzle (896 % 8 == 0)
  const int kn = wg & 1;
  const int mh = wg >> 1;
  const int hp = mh % 28;
  const int n = mh / 28;
  const int h0 = hp * 2;

  const unsigned char* xpb = (const unsigned char*)xp;
  const unsigned char* wtb = (const unsigned char*)wt;

  // per-lane A source offsets (px = q*64 + lane; px>=112 -> zeroed halo cell)
  int offA0, offA1;
  {
    int dr = (lane >= 56) ? 1 : 0;
    offA0 = dr * ROWB + (lane - 56 * dr) * 16;            // px 0..63
    offA1 = (lane < 48) ? (ROWB + (8 + lane) * 16)        // px 64..111
                        : (57 * 16);                      // pad px: zero cell
  }

  auto issue = [&](int t, unsigned char* dst) {
    const int rs = t >> 2;
    const int cs = t & 3;
    const int fr = (rs * 11) >> 5;  // rs/3
    const int fs = rs - fr * 3;
#pragma unroll
    for (int pi = 0; pi < 2; ++pi) {
      const int p = wv * 2 + pi;
      const size_t ab =
          (((size_t)(n * 58 + h0 + fr) * 16 + (cs * 4 + p)) * 66 + fs) * 16;
      gload_lds16(xpb + ab + offA0, dst + p * 2048 + lane * 16);
      gload_lds16(xpb + ab + offA1, dst + p * 2048 + 1024 + lane * 16);
      gload_lds16(wtb + (((t * 2 + kn) * 4 + p) << 10) + lane * 16,
                  dst + 8192 + p * 1024 + lane * 16);
    }
  };

  issue(0, xs);
  issue(1, xs + BUFSZ);
  issue(2, xs + 2 * BUFSZ);

  f32x4 acc[4][4] = {};  // [am][bn]
  const int fo = (lane >> 4) * 2048 + (lane & 15) * 16;   // A frag base
  const int fob = (lane >> 4) * 1024 + (lane & 15) * 16;  // B frag base

#pragma unroll 1
  for (int t = 0; t < 36; ++t) {
    if (t < 34)
      asm volatile("s_waitcnt vmcnt(12)" ::: "memory");
    else if (t == 34)
      asm volatile("s_waitcnt vmcnt(6)" ::: "memory");
    else
      asm volatile("s_waitcnt vmcnt(0)" ::: "memory");
    __builtin_amdgcn_s_barrier();

    if (t < 33) issue(t + 3, xs + ((t + 3) & 3) * BUFSZ);

    const unsigned char* buf = xs + (t & 3) * BUFSZ;
    bf16x8 Af[4], Bf[4];
#pragma unroll
    for (int am = 0; am < 4; ++am)
      Af[am] = *(const bf16x8*)(buf + fo + (wv * 64 + am * 16) * 16);
#pragma unroll
    for (int bn = 0; bn < 4; ++bn)
      Bf[bn] = *(const bf16x8*)(buf + 8192 + fob + bn * 16 * 16);

    __builtin_amdgcn_s_setprio(1);
#pragma unroll
    for (int am = 0; am < 4; ++am)
#pragma unroll
      for (int bn = 0; bn < 4; ++bn)
        acc[am][bn] = __builtin_amdgcn_mfma_f32_16x16x32_bf16(
            Af[am], Bf[bn], acc[am][bn], 0, 0, 0);
    __builtin_amdgcn_s_setprio(0);
  }

  // epilogue: D row(px) = (lane>>4)*4 + j, col(k) = lane&15; px = wv*64+am*16+row
  const int q4 = (lane >> 4) << 2;
#pragma unroll
  for (int am = 0; am < 4; ++am) {
    const int pxb = wv * 64 + am * 16 + q4;
    if (pxb < 112) {
      const int dr = (pxb >= 56) ? 1 : 0;
      const int w0 = pxb - 56 * dr;
      const int h = h0 + dr;
#pragma unroll
      for (int bn = 0; bn < 4; ++bn) {
        const int k = kn * 64 + bn * 16 + (lane & 15);
        float* op = out + ((size_t)(n * KK + k) * HH + h) * WW + w0;
        *(f32x4*)op = acc[am][bn];
      }
    }
  }
}

extern "C" void kernel_launch(void* const* d_in, const int* in_sizes, int n_in,
                              void* d_out, int out_size, void* d_ws, size_t ws_size,
                              hipStream_t stream) {
  const float* x = (const float*)d_in[0];
  const float* kin = (const float*)d_in[1];
  float* out = (float*)d_out;
  unsigned short* wt = (unsigned short*)d_ws;                    // 288 KB
  unsigned short* xp = (unsigned short*)((char*)d_ws + XP_OFF);  // 15.7 MB

  hipLaunchKernelGGL(prep_kernel, dim3(4404), dim3(256), 0, stream, x, kin, xp, wt);
  hipLaunchKernelGGL(conv_kernel, dim3(896), dim3(128), 0, stream, xp, wt, out);
}